// Round 9
// baseline (139.833 us; speedup 1.0000x reference)
//
#include <hip/hip_runtime.h>

// VQ: x (16,64,64,64) f32, codebook e (64,1024) f32. N=65536, D=64, K=1024.
//
// R15: R14's null result (2x occupancy, same 53us tile loop) + counter
// re-fit (VALUBusy/MfmaUtil imply ~0.7GHz effective clock during short
// dispatches) => binding resource is the per-CU LDS read port: each wave
// re-reads the full 4KB B-tile per k-tile (2048 ds_read_b128 wave-ops/CU
// ~= 25K port-cycles ~= the 52.5us wall at low clock). Fix: double B-reuse
// per byte read: mt 2 -> 4 (wave owns 64 positions; 24 MFMAs per 4KB tile
// read). Block = 4 waves x 64 pos = 256 positions, grid = 256 (1 block/CU):
// per-CU LDS reads halve (2048 -> 1024 wave-ops), staging writes halve.
//  - __launch_bounds__(256,1): VGPR ~160 expected (A-frags 64 + top2 state
//    48 + B 16 + acc 16 + misc); 1 wave/SIMD is fine (R14: occupancy is not
//    the lever); 4 independent acc chains give in-wave MFMA ILP.
// Everything else proven-verbatim: register-staged LDS double buffer,
// 3-term split-bf16 (xh*eh + xl*eh + xh*el), m = x.e - 0.5*c2 via acc-init,
// argMAX, fmed3 second-best (R14-verified), certify iff m1-m2 > MARGIN/2,
// block-local worklist, R13 wave-parallel bit-exact np-scan resolve,
// single STE write phase.

#define D 64
#define K 1024
#define NPOS 65536
#define HW 4096
#define XSTRIDE 262144  // D*HW
#define MARGIN 1.0e-3f

typedef float vfloat4 __attribute__((ext_vector_type(4)));
typedef short short8  __attribute__((ext_vector_type(8)));

static __device__ __forceinline__ unsigned short bf16_rne(float f) {
    unsigned u = __float_as_uint(f);
    u += 0x7FFFu + ((u >> 16) & 1u);
    return (unsigned short)(u >> 16);
}
static __device__ __forceinline__ float bf16_to_f32(unsigned short h) {
    return __uint_as_float(((unsigned)h) << 16);
}

// ---- prep: codebook -> bf16 split B-fragments + c2n = -0.5*sum(e^2) -------
// frag layout: ebf[tile][s][split][lane][j], lane=q*16+n, value =
// split(e[d][k]), d=s*32+q*8+j, k=tile*16+n. Thread t of the main kernel
// owns 16B at t*16 within a tile: stage load + ds_write are linear copies.
__global__ void vq_prep(const float* __restrict__ e,
                        unsigned short* __restrict__ ebf,
                        float* __restrict__ c2n) {
    const int tile = blockIdx.x;               // 0..63
    const int t = threadIdx.x;
    const int n = t & 15;
    const int dg = t >> 4;                     // 0..15
#pragma unroll
    for (int i = 0; i < 4; ++i) {
        const int d = dg * 4 + i;
        const float v = e[d * K + tile * 16 + n];
        const unsigned short hh = bf16_rne(v);
        const float rem = v - bf16_to_f32(hh);     // exact (Sterbenz)
        const unsigned short hl = bf16_rne(rem);
        const int s = d >> 5, q = (d >> 3) & 3, j = d & 7;
        const int lanei = q * 16 + n;
        ebf[(((tile * 2 + s) * 2 + 0) * 64 + lanei) * 8 + j] = hh;
        ebf[(((tile * 2 + s) * 2 + 1) * 64 + lanei) * 8 + j] = hl;
    }
    if (t < 16) {
        const int k = tile * 16 + t;
        float s = 0.f;
#pragma unroll
        for (int d = 0; d < D; ++d) {
            const float v = e[d * K + k];      // sequential-d rounded squares
            s = s + __fmul_rn(v, v);
        }
        c2n[k] = -0.5f * s;
    }
}

// ---- main: 256 blocks x 256 threads; block = 256 positions, 4 waves -------
// wave owns 64 positions (4 M-tiles); 24 MFMAs per 4KB B-tile read.
__global__ __launch_bounds__(256, 1)
void vq_main(const float* __restrict__ x, const float* __restrict__ e,
             const unsigned short* __restrict__ ebf,
             const float* __restrict__ c2n,
             float* __restrict__ out) {
    __shared__ __align__(16) unsigned short lds_e[2][2048];  // 2 x 4 KB tiles
    __shared__ int   bk_lds[256];
    __shared__ int   lwl[256];
    __shared__ int   lwl_count;
    const int t = threadIdx.x;
    const int lane = t & 63;
    const int w = t >> 6;                      // wave 0..3 = position group
    const int p0 = blockIdx.x * 256;
    const int b = p0 >> 12;                    // 256 | 4096 -> single b
    const int sp0 = p0 & (HW - 1);
    const int n = lane & 15;                   // A-row m / B-col n / C col
    const int q = lane >> 4;                   // k-quad / C row group

    if (t == 0) lwl_count = 0;

    // A-frags (registers): xh/xl for 4 M-tiles x 2 K-steps
    short8 ah[4][2], al[4][2];
#pragma unroll
    for (int mt = 0; mt < 4; ++mt) {
        const int spc = sp0 + w * 64 + mt * 16 + n;
#pragma unroll
        for (int s = 0; s < 2; ++s) {
            short8 fh, fl_;
#pragma unroll
            for (int j = 0; j < 8; ++j) {
                const int d = s * 32 + q * 8 + j;      // A[m=n][k=q*8+j]
                const float v = x[(size_t)b * XSTRIDE + (size_t)d * HW + spc];
                const unsigned short h = bf16_rne(v);
                fh[j] = (short)h;
                fl_[j] = (short)bf16_rne(v - bf16_to_f32(h));
            }
            ah[mt][s] = fh; al[mt][s] = fl_;
        }
    }

    // stage tile 0: global -> reg -> LDS (thread t owns 16B at t*16)
    {
        const short8 stg = *(const short8*)(ebf + t * 8);
        *(short8*)(&lds_e[0][t * 8]) = stg;
    }

    float s1[4][4], s2[4][4]; int t1[4][4];
#pragma unroll
    for (int mt = 0; mt < 4; ++mt)
#pragma unroll
        for (int r = 0; r < 4; ++r) { s1[mt][r] = -3.4e38f; s2[mt][r] = -3.4e38f; t1[mt][r] = 0; }

    __syncthreads();                           // tile 0 in LDS + lwl_count=0

    for (int tt = 0; tt < 64; ++tt) {
        const int cur = tt & 1;
        short8 stg;
        if (tt < 63)                           // issue early: hide L2 latency
            stg = *(const short8*)(ebf + (size_t)(tt + 1) * 2048 + t * 8);
        const short8* fb = (const short8*)(&lds_e[cur][0]);
        const short8 bh0 = fb[lane];           // s0 hi
        const short8 bl0 = fb[64 + lane];      // s0 lo
        const short8 bh1 = fb[128 + lane];     // s1 hi
        const short8 bl1 = fb[192 + lane];     // s1 lo
        const float c2v = c2n[tt * 16 + n];
#pragma unroll
        for (int mt = 0; mt < 4; ++mt) {
            vfloat4 acc = {c2v, c2v, c2v, c2v};    // m = x.e - 0.5*c2
            acc = __builtin_amdgcn_mfma_f32_16x16x32_bf16(ah[mt][0], bh0, acc, 0, 0, 0);
            acc = __builtin_amdgcn_mfma_f32_16x16x32_bf16(ah[mt][1], bh1, acc, 0, 0, 0);
            acc = __builtin_amdgcn_mfma_f32_16x16x32_bf16(al[mt][0], bh0, acc, 0, 0, 0);
            acc = __builtin_amdgcn_mfma_f32_16x16x32_bf16(al[mt][1], bh1, acc, 0, 0, 0);
            acc = __builtin_amdgcn_mfma_f32_16x16x32_bf16(ah[mt][0], bl0, acc, 0, 0, 0);
            acc = __builtin_amdgcn_mfma_f32_16x16x32_bf16(ah[mt][1], bl1, acc, 0, 0, 0);
#pragma unroll
            for (int r = 0; r < 4; ++r) {      // C/D: row=q*4+r, col=n; argMAX
                const float m = acc[r];
                const bool gt = m > s1[mt][r];
                // second-best: median of (m, s1, s2) correct in all cases
                s2[mt][r] = __builtin_amdgcn_fmed3f(m, s1[mt][r], s2[mt][r]);
                s1[mt][r] = fmaxf(s1[mt][r], m);
                t1[mt][r] = gt ? tt : t1[mt][r];
            }
        }
        if (tt < 63)                           // reg dep forces vmcnt wait
            *(short8*)(&lds_e[cur ^ 1][t * 8]) = stg;
        __syncthreads();                       // ds_write visible to all waves
    }

    // merge top-2 across the 16 code-columns; certify; push LOCAL worklist
#pragma unroll
    for (int mt = 0; mt < 4; ++mt)
#pragma unroll
        for (int r = 0; r < 4; ++r) {
            float a1 = s1[mt][r], a2 = s2[mt][r];
            int ak = t1[mt][r] * 16 + n;
#pragma unroll
            for (int m = 1; m < 16; m <<= 1) {
                const float o1 = __shfl_xor(a1, m, 64);
                const float o2 = __shfl_xor(a2, m, 64);
                const int   ok = __shfl_xor(ak, m, 64);
                const bool take = (o1 > a1) || (o1 == a1 && ok < ak);
                const float loser = take ? a1 : o1;
                a1 = take ? o1 : a1;
                ak = take ? ok : ak;
                a2 = fmaxf(fmaxf(a2, o2), loser);
            }
            if (n == 0) {
                const int pl = w * 64 + mt * 16 + q * 4 + r;
                bk_lds[pl] = ak;
                if (a1 - a2 <= 0.5f * MARGIN) {   // score gap = 2*(m1-m2)
                    const int idx = atomicAdd(&lwl_count, 1);
                    lwl[idx] = pl;
                }
            }
        }
    __syncthreads();

    // per-WAVE exact resolve (R9/R13-verified shfl-broadcast bit-exact scan):
    // one ambiguous position per wave, no barriers, disjoint bk_lds writes.
    const int cnt = lwl_count;                 // uniform after barrier
    for (int i = w; i < cnt; i += 4) {
        const int pl = lwl[i];
        const int sp = sp0 + pl;
        // lane holds channel d=lane of this position; broadcast via shfl
        const float myx = x[(size_t)b * XSTRIDE + (size_t)lane * HW + sp];
        // Ap = np.sum(x**2) in numpy pairwise-8 order (verified grouping)
        float r8[8];
#pragma unroll
        for (int i0 = 0; i0 < 8; ++i0) {
            const float v = __shfl(myx, i0, 64);
            r8[i0] = __fmul_rn(v, v);
        }
#pragma unroll
        for (int j = 1; j < 8; ++j)
#pragma unroll
            for (int i0 = 0; i0 < 8; ++i0) {
                const float v = __shfl(myx, 8 * j + i0, 64);
                r8[i0] = r8[i0] + __fmul_rn(v, v);
            }
        const float Ap = ((r8[0] + r8[1]) + (r8[2] + r8[3])) + ((r8[4] + r8[5]) + (r8[6] + r8[7]));
        // 16 codes per lane (k = lane*16+m); sequential-d FMA chain per code
        float acc[16];
#pragma unroll
        for (int m = 0; m < 16; ++m) acc[m] = 0.f;
#pragma unroll 4
        for (int d = 0; d < D; ++d) {
            const float xd = __shfl(myx, d, 64);
            const vfloat4 e0 = *(const vfloat4*)(e + d * K + lane * 16);
            const vfloat4 e1 = *(const vfloat4*)(e + d * K + lane * 16 + 4);
            const vfloat4 e2 = *(const vfloat4*)(e + d * K + lane * 16 + 8);
            const vfloat4 e3 = *(const vfloat4*)(e + d * K + lane * 16 + 12);
#pragma unroll
            for (int c = 0; c < 4; ++c) {
                acc[c]      = __builtin_fmaf(xd, e0[c], acc[c]);
                acc[4 + c]  = __builtin_fmaf(xd, e1[c], acc[4 + c]);
                acc[8 + c]  = __builtin_fmaf(xd, e2[c], acc[8 + c]);
                acc[12 + c] = __builtin_fmaf(xd, e3[c], acc[12 + c]);
            }
        }
        float bs = 3.4e38f; int bk = 0x7fffffff;
#pragma unroll
        for (int m = 0; m < 16; ++m) {
            const int k = lane * 16 + m;       // ascending k per lane
            const float c2k = -2.0f * c2n[k];  // exact pow2 scale = np c2[k]
            const float sc = __builtin_fmaf(-2.f, acc[m], Ap) + c2k;
            if (sc < bs || (sc == bs && k < bk)) { bs = sc; bk = k; }
        }
#pragma unroll
        for (int mm = 1; mm < 64; mm <<= 1) {  // lane-major k order = global
            const float os = __shfl_xor(bs, mm, 64);
            const int   ok = __shfl_xor(bk, mm, 64);
            if (os < bs || (os == bs && ok < bk)) { bs = os; bk = ok; }
        }
        if (lane == 0) bk_lds[pl] = bk;        // exact index replaces approx
    }
    __syncthreads();

    // single STE write phase: 256 positions x 64 channels (thread = position)
    const int pl = t;
    const int bk = bk_lds[pl];
    const int sp = sp0 + pl;
    const float* xb = x + (size_t)b * XSTRIDE + sp;
    float* ob = out + (size_t)b * XSTRIDE + sp;
#pragma unroll 8
    for (int c = 0; c < 64; ++c) {
        const float xq = xb[(size_t)c * HW];
        const float qv = e[c * K + bk];
        ob[(size_t)c * HW] = xq + (qv - xq);   // np STE: fl(x + fl(q-x))
    }
}

extern "C" void kernel_launch(void* const* d_in, const int* in_sizes, int n_in,
                              void* d_out, int out_size, void* d_ws, size_t ws_size,
                              hipStream_t stream) {
    const float* x = (const float*)d_in[0];
    const float* e = (const float*)d_in[1];
    float* out = (float*)d_out;

    char* ws = (char*)d_ws;                          // ~260 KB used
    unsigned short* ebf = (unsigned short*)ws;       // 256 KB B-fragments
    float* c2n = (float*)(ws + 262144);              // 4 KB  (-0.5*sum e^2)

    vq_prep<<<64, 256, 0, stream>>>(e, ebf, c2n);
    vq_main<<<NPOS / 256, 256, 0, stream>>>(x, e, ebf, c2n, out);
}

// Round 10
// 127.157 us; speedup vs baseline: 1.0997x; 1.0997x over previous
//
#include <hip/hip_runtime.h>

// VQ: x (16,64,64,64) f32, codebook e (64,1024) f32. N=65536, D=64, K=1024.
//
// R16: R14 (more TLP: null) + R15 (fewer LDS reads, less TLP: regress)
// falsify occupancy/L2/LDS theories. Remaining suspect: the per-score
// instruction stream (64 barrier-locked iters x {6 serial MFMA + top-2 VALU
// + loop overhead}). Attack it with the 32x32x16 MFMA shape: 2x FLOP/instr
// => 12 MFMAs per 32-code k-tile (was 24 via 16x16), 32 iterations (was 64):
// halves MFMA issues, barriers, acc-inits, staging instrs; same LDS bytes;
// same per-score top-2 VALU.
//  - fragments (extending the verified 16x16 pattern): A row=lane&31,
//    k=(lane>>5)*8+j; B col=lane&31, same k; C/D col=lane&31,
//    row=(r&3)+8*(r>>2)+4*(lane>>5) [guide m74/m101-verified].
//  - wave owns 32 positions; ks-loop 0..3 {2 ds_read_b128, 3 MFMA} keeps
//    only 8 B-regs live (VGPR ~124, fits (256,2) cap of 128).
//  - merge butterfly masks 1..16 stay within each 32-lane half; lanes 0/32
//    write+certify 16 positions each; code = t1*32 + (lane&31).
// Rest proven-verbatim: 3-term split-bf16 (xh*eh + xl*eh + xh*el),
// m = x.e - 0.5*c2 via acc-init, argMAX, fmed3 second-best, certify iff
// m1-m2 > MARGIN/2, block-local worklist, R13 wave-parallel bit-exact
// np-scan resolve, single STE write phase.

#define D 64
#define K 1024
#define NPOS 65536
#define HW 4096
#define XSTRIDE 262144  // D*HW
#define MARGIN 1.0e-3f

typedef float vfloat4  __attribute__((ext_vector_type(4)));
typedef float vfloat16 __attribute__((ext_vector_type(16)));
typedef short short8   __attribute__((ext_vector_type(8)));

static __device__ __forceinline__ unsigned short bf16_rne(float f) {
    unsigned u = __float_as_uint(f);
    u += 0x7FFFu + ((u >> 16) & 1u);
    return (unsigned short)(u >> 16);
}
static __device__ __forceinline__ float bf16_to_f32(unsigned short h) {
    return __uint_as_float(((unsigned)h) << 16);
}

// ---- prep: codebook -> bf16 split 32x32-B-fragments + c2n = -0.5*sum(e^2) -
// frag layout: ebf[tile][ks][split][lane][j], value = split(e[d][k]),
// d = ks*16 + (lane>>5)*8 + j, k = tile*32 + (lane&31). Tile = 8 KB.
// Thread t of main owns 16B at t*16 within each half: linear copies.
__global__ void vq_prep(const float* __restrict__ e,
                        unsigned short* __restrict__ ebf,
                        float* __restrict__ c2n) {
    const int tile = blockIdx.x;               // 0..31
    const int t = threadIdx.x;
    const int l = t & 63;
    const int ks = t >> 6;                     // 0..3
    const int k = tile * 32 + (l & 31);
#pragma unroll
    for (int j = 0; j < 8; ++j) {
        const int d = ks * 16 + (l >> 5) * 8 + j;
        const float v = e[d * K + k];
        const unsigned short hh = bf16_rne(v);
        const float rem = v - bf16_to_f32(hh);     // exact (Sterbenz)
        const unsigned short hl = bf16_rne(rem);
        ebf[((size_t)(tile * 8 + ks * 2 + 0) * 64 + l) * 8 + j] = hh;
        ebf[((size_t)(tile * 8 + ks * 2 + 1) * 64 + l) * 8 + j] = hl;
    }
    if (t < 32) {
        const int kk = tile * 32 + t;
        float s = 0.f;
#pragma unroll
        for (int d = 0; d < D; ++d) {
            const float v = e[d * K + kk];     // sequential-d rounded squares
            s = s + __fmul_rn(v, v);
        }
        c2n[kk] = -0.5f * s;
    }
}

// ---- main: 512 blocks x 256 threads; block = 128 positions, 4 waves -------
// wave owns 32 positions; 32 k-tiles of 32 codes; 12 MFMA (32x32x16) each.
__global__ __launch_bounds__(256, 2)
void vq_main(const float* __restrict__ x, const float* __restrict__ e,
             const unsigned short* __restrict__ ebf,
             const float* __restrict__ c2n,
             float* __restrict__ out) {
    __shared__ __align__(16) unsigned short lds_e[2][4096];  // 2 x 8 KB tiles
    __shared__ int   bk_lds[128];
    __shared__ int   lwl[128];
    __shared__ int   lwl_count;
    const int t = threadIdx.x;
    const int lane = t & 63;
    const int w = t >> 6;                      // wave 0..3 = position group
    const int p0 = blockIdx.x * 128;
    const int b = p0 >> 12;                    // 128 | 4096 -> single b
    const int sp0 = p0 & (HW - 1);
    const int c31 = lane & 31;                 // code column / A row
    const int hi = lane >> 5;                  // k-group half

    if (t == 0) lwl_count = 0;

    // A-frags (registers): xh/xl for 4 K-steps (K=16 each)
    short8 ah[4], al[4];
    {
        const int spc = sp0 + w * 32 + c31;    // this lane's position
#pragma unroll
        for (int ks = 0; ks < 4; ++ks) {
            short8 fh, fl_;
#pragma unroll
            for (int j = 0; j < 8; ++j) {
                const int d = ks * 16 + hi * 8 + j;    // A[row=c31][k]
                const float v = x[(size_t)b * XSTRIDE + (size_t)d * HW + spc];
                const unsigned short h = bf16_rne(v);
                fh[j] = (short)h;
                fl_[j] = (short)bf16_rne(v - bf16_to_f32(h));
            }
            ah[ks] = fh; al[ks] = fl_;
        }
    }

    // stage tile 0: global -> reg -> LDS (thread t owns 2 x 16B)
    {
        const short8 s0 = *(const short8*)(ebf + t * 8);
        const short8 s1v = *(const short8*)(ebf + 2048 + t * 8);
        *(short8*)(&lds_e[0][t * 8]) = s0;
        *(short8*)(&lds_e[0][2048 + t * 8]) = s1v;
    }

    float s1[16], s2[16]; int t1[16];
#pragma unroll
    for (int r = 0; r < 16; ++r) { s1[r] = -3.4e38f; s2[r] = -3.4e38f; t1[r] = 0; }

    __syncthreads();                           // tile 0 in LDS + lwl_count=0

    for (int tt = 0; tt < 32; ++tt) {
        const int cur = tt & 1;
        short8 stg0, stg1;
        if (tt < 31) {                         // issue early: hide L2 latency
            stg0 = *(const short8*)(ebf + (size_t)(tt + 1) * 4096 + t * 8);
            stg1 = *(const short8*)(ebf + (size_t)(tt + 1) * 4096 + 2048 + t * 8);
        }
        const short8* fb = (const short8*)(&lds_e[cur][0]);
        const float c2v = c2n[tt * 32 + c31];
        vfloat16 acc;
#pragma unroll
        for (int r = 0; r < 16; ++r) acc[r] = c2v;   // m = x.e - 0.5*c2
#pragma unroll
        for (int ks = 0; ks < 4; ++ks) {       // only 8 B-regs live at a time
            const short8 bh = fb[(ks * 2 + 0) * 64 + lane];
            const short8 bl = fb[(ks * 2 + 1) * 64 + lane];
            acc = __builtin_amdgcn_mfma_f32_32x32x16_bf16(ah[ks], bh, acc, 0, 0, 0);
            acc = __builtin_amdgcn_mfma_f32_32x32x16_bf16(al[ks], bh, acc, 0, 0, 0);
            acc = __builtin_amdgcn_mfma_f32_32x32x16_bf16(ah[ks], bl, acc, 0, 0, 0);
        }
#pragma unroll
        for (int r = 0; r < 16; ++r) {         // C/D: col=c31, row via r,hi
            const float m = acc[r];
            const bool gt = m > s1[r];
            s2[r] = __builtin_amdgcn_fmed3f(m, s1[r], s2[r]);  // second-best
            s1[r] = fmaxf(s1[r], m);
            t1[r] = gt ? tt : t1[r];
        }
        if (tt < 31) {                         // reg dep forces vmcnt wait
            *(short8*)(&lds_e[cur ^ 1][t * 8]) = stg0;
            *(short8*)(&lds_e[cur ^ 1][2048 + t * 8]) = stg1;
        }
        __syncthreads();                       // ds_write visible to all waves
    }

    // merge top-2 across the 32 code-columns (within each 32-lane half);
    // certify; push LOCAL worklist. Lanes 0 and 32 own 16 positions each.
#pragma unroll
    for (int r = 0; r < 16; ++r) {
        float a1 = s1[r], a2 = s2[r];
        int ak = t1[r] * 32 + c31;
#pragma unroll
        for (int m = 1; m < 32; m <<= 1) {     // masks <32 stay in-half
            const float o1 = __shfl_xor(a1, m, 64);
            const float o2 = __shfl_xor(a2, m, 64);
            const int   ok = __shfl_xor(ak, m, 64);
            const bool take = (o1 > a1) || (o1 == a1 && ok < ak);
            const float loser = take ? a1 : o1;
            a1 = take ? o1 : a1;
            ak = take ? ok : ak;
            a2 = fmaxf(fmaxf(a2, o2), loser);
        }
        if (c31 == 0) {
            const int pl = w * 32 + (r & 3) + 8 * (r >> 2) + hi * 4;
            bk_lds[pl] = ak;
            if (a1 - a2 <= 0.5f * MARGIN) {    // score gap = 2*(m1-m2)
                const int idx = atomicAdd(&lwl_count, 1);
                lwl[idx] = pl;
            }
        }
    }
    __syncthreads();

    // per-WAVE exact resolve (R9/R13-verified shfl-broadcast bit-exact scan):
    // one ambiguous position per wave, no barriers, disjoint bk_lds writes.
    const int cnt = lwl_count;                 // uniform after barrier
    for (int i = w; i < cnt; i += 4) {
        const int pl = lwl[i];
        const int sp = sp0 + pl;
        // lane holds channel d=lane of this position; broadcast via shfl
        const float myx = x[(size_t)b * XSTRIDE + (size_t)lane * HW + sp];
        // Ap = np.sum(x**2) in numpy pairwise-8 order (verified grouping)
        float r8[8];
#pragma unroll
        for (int i0 = 0; i0 < 8; ++i0) {
            const float v = __shfl(myx, i0, 64);
            r8[i0] = __fmul_rn(v, v);
        }
#pragma unroll
        for (int j = 1; j < 8; ++j)
#pragma unroll
            for (int i0 = 0; i0 < 8; ++i0) {
                const float v = __shfl(myx, 8 * j + i0, 64);
                r8[i0] = r8[i0] + __fmul_rn(v, v);
            }
        const float Ap = ((r8[0] + r8[1]) + (r8[2] + r8[3])) + ((r8[4] + r8[5]) + (r8[6] + r8[7]));
        // 16 codes per lane (k = lane*16+m); sequential-d FMA chain per code
        float acc[16];
#pragma unroll
        for (int m = 0; m < 16; ++m) acc[m] = 0.f;
#pragma unroll 4
        for (int d = 0; d < D; ++d) {
            const float xd = __shfl(myx, d, 64);
            const vfloat4 e0 = *(const vfloat4*)(e + d * K + lane * 16);
            const vfloat4 e1 = *(const vfloat4*)(e + d * K + lane * 16 + 4);
            const vfloat4 e2 = *(const vfloat4*)(e + d * K + lane * 16 + 8);
            const vfloat4 e3 = *(const vfloat4*)(e + d * K + lane * 16 + 12);
#pragma unroll
            for (int c = 0; c < 4; ++c) {
                acc[c]      = __builtin_fmaf(xd, e0[c], acc[c]);
                acc[4 + c]  = __builtin_fmaf(xd, e1[c], acc[4 + c]);
                acc[8 + c]  = __builtin_fmaf(xd, e2[c], acc[8 + c]);
                acc[12 + c] = __builtin_fmaf(xd, e3[c], acc[12 + c]);
            }
        }
        float bs = 3.4e38f; int bk = 0x7fffffff;
#pragma unroll
        for (int m = 0; m < 16; ++m) {
            const int k = lane * 16 + m;       // ascending k per lane
            const float c2k = -2.0f * c2n[k];  // exact pow2 scale = np c2[k]
            const float sc = __builtin_fmaf(-2.f, acc[m], Ap) + c2k;
            if (sc < bs || (sc == bs && k < bk)) { bs = sc; bk = k; }
        }
#pragma unroll
        for (int mm = 1; mm < 64; mm <<= 1) {  // lane-major k order = global
            const float os = __shfl_xor(bs, mm, 64);
            const int   ok = __shfl_xor(bk, mm, 64);
            if (os < bs || (os == bs && ok < bk)) { bs = os; bk = ok; }
        }
        if (lane == 0) bk_lds[pl] = bk;        // exact index replaces approx
    }
    __syncthreads();

    // single STE write phase: 128 positions x 64 channels
    const int pl = t & 127;
    const int half = t >> 7;
    const int bk = bk_lds[pl];
    const int sp = sp0 + pl;
    const float* xb = x + (size_t)b * XSTRIDE + sp;
    float* ob = out + (size_t)b * XSTRIDE + sp;
#pragma unroll
    for (int i = 0; i < 32; ++i) {
        const int c = half * 32 + i;
        const float xq = xb[(size_t)c * HW];
        const float qv = e[c * K + bk];
        ob[(size_t)c * HW] = xq + (qv - xq);   // np STE: fl(x + fl(q-x))
    }
}

extern "C" void kernel_launch(void* const* d_in, const int* in_sizes, int n_in,
                              void* d_out, int out_size, void* d_ws, size_t ws_size,
                              hipStream_t stream) {
    const float* x = (const float*)d_in[0];
    const float* e = (const float*)d_in[1];
    float* out = (float*)d_out;

    char* ws = (char*)d_ws;                          // ~260 KB used
    unsigned short* ebf = (unsigned short*)ws;       // 256 KB B-fragments
    float* c2n = (float*)(ws + 262144);              // 4 KB  (-0.5*sum e^2)

    vq_prep<<<32, 256, 0, stream>>>(e, ebf, c2n);
    vq_main<<<NPOS / 128, 256, 0, stream>>>(x, e, ebf, c2n, out);
}